// Round 11
// baseline (250.748 us; speedup 1.0000x reference)
//
#include <hip/hip_runtime.h>

// Problem constants (match reference)
#define DHW   (128*128*128)        // 2^21
#define CDHW  (4*DHW)              // 2^23
#define NTOT  (2*CDHW)             // 2^24 = 16,777,216
#define NSITE (2*DHW)              // B*DHW = 2^22 sites
#define NACC  1024                 // one accumulator slot per erode block

// erode2 tiling: full x-row (32 f4), 8 owned y-rows, 16 owned z-planes.
#define ROW4     32
#define IN_ROWS  12                // 8 + 2*2 y-halo
#define S1_ROWS  10                // 8 + 2*1
#define IN_P4    (IN_ROWS*ROW4)    // 384 f4 / input plane
#define S1_P4    (S1_ROWS*ROW4)    // 320 f4 / s1 plane
#define SLOT4(z) (((z)+8)&3)       // input ring: 4 slots
#define SLOT2(z) (((z)+8)&1)       // s1 ring: 2 slots

// Kernel A: softmax over C=4, subtract one-hot(target), square -> buf0.
// ALL 20 loads (4 site-groups x {4 class float4 + int4}) are hoisted into a
// pure load phase so the wave has 20 outstanding loads (MLP), then a
// compute+store phase. Zeros accs.
__global__ __launch_bounds__(256) void softmax_sq_kernel(
    const float* __restrict__ in, const int* __restrict__ tgt,
    float* __restrict__ out, double* __restrict__ accs)
{
    int tid = threadIdx.x;
    int gid = blockIdx.x * 256 + tid;
    if (gid < NACC) accs[gid] = 0.0;

    float4 A0[4], A1[4], A2[4], A3[4];
    int4   T[4];
    int j0 = blockIdx.x * 1024 + tid;             // f4-group index base

    // ---- load phase: issue everything ----
    #pragma unroll
    for (int h = 0; h < 4; ++h) {
        int base = (j0 + h * 256) << 2;           // site index
        int b = base >> 21;
        int s = base & (DHW - 1);
        const float* p = in + (size_t)b * CDHW + s;
        A0[h] = *(const float4*)(p);
        A1[h] = *(const float4*)(p + DHW);
        A2[h] = *(const float4*)(p + 2 * DHW);
        A3[h] = *(const float4*)(p + 3 * DHW);
        T[h]  = *(const int4*)(tgt + base);
    }

    // ---- compute + store phase ----
    #pragma unroll
    for (int h = 0; h < 4; ++h) {
        int base = (j0 + h * 256) << 2;
        int b = base >> 21;
        int s = base & (DHW - 1);
        float4 a0 = A0[h], a1 = A1[h], a2 = A2[h], a3 = A3[h];
        int4   t  = T[h];
        float4 o0, o1, o2, o3;
        #define SOFTMAX1(K)                                                    \
        {                                                                      \
            float v0 = a0.K, v1 = a1.K, v2 = a2.K, v3 = a3.K;                  \
            float m  = fmaxf(fmaxf(v0, v1), fmaxf(v2, v3));                    \
            float e0 = expf(v0 - m), e1 = expf(v1 - m);                        \
            float e2 = expf(v2 - m), e3 = expf(v3 - m);                        \
            float inv = 1.0f / (e0 + e1 + e2 + e3);                            \
            int   tv = t.K;                                                    \
            float d0 = e0 * inv - (tv == 0 ? 1.0f : 0.0f);                     \
            float d1 = e1 * inv - (tv == 1 ? 1.0f : 0.0f);                     \
            float d2 = e2 * inv - (tv == 2 ? 1.0f : 0.0f);                     \
            float d3 = e3 * inv - (tv == 3 ? 1.0f : 0.0f);                     \
            o0.K = d0 * d0; o1.K = d1 * d1; o2.K = d2 * d2; o3.K = d3 * d3;    \
        }
        SOFTMAX1(x) SOFTMAX1(y) SOFTMAX1(z) SOFTMAX1(w)
        #undef SOFTMAX1
        float* q = out + (size_t)b * CDHW + s;
        *(float4*)(q)           = o0;
        *(float4*)(q + DHW)     = o1;
        *(float4*)(q + 2 * DHW) = o2;
        *(float4*)(q + 3 * DHW) = o3;
    }
}

// Kernel B: TWO fused erosion steps; z-marching rolling planes.
// Primary s1 row = trow+1 (always y-valid) so each thread's s2 center and
// z-neighbors live in a 3-deep register chain. Input ring = 4 slots, s1
// ring = 2 slots -> ONE barrier per plane. x-neighbors via lane shuffles.
__global__ __launch_bounds__(256, 4) void erode2_kernel(
    const float4* __restrict__ src, float4* __restrict__ dst,
    const float* __restrict__ kern, const float* __restrict__ bias,
    const float* __restrict__ weight, float c1, float c2,
    int store, double* __restrict__ accs)
{
    __shared__ float4 lin[4 * IN_P4];   // 24.6 KB
    __shared__ float4 ls1[2 * S1_P4];   // 10.2 KB
    __shared__ double wsum[4];

    const int tid = threadIdx.x;
    const int bid = blockIdx.x;
    const int y0 = (bid & 15) << 3;
    const int zb = ((bid >> 4) & 7) << 4;
    const int bc = bid >> 7;            // b*4 + c in [0,8)

    const float4* sp = src + ((size_t)bc << 19);   // slab = 2^19 f4
    float4*       dp = dst + ((size_t)bc << 19);
    const float wk = kern[13];          // all 7 taps equal
    const float bs = bias[bc & 3];

    const int col  = tid & 31;
    const int trow = tid >> 5;

    // ---- commit maps (input rows 0..11 <-> gy = y0+row-2) ----
    const int  gy0  = y0 + trow - 2;               // rows 0..7
    const bool lv0  = ((unsigned)gy0 < 128u);
    const int  off0 = (lv0 ? gy0 : 0) * 32 + col;
    const bool act1 = (tid < 128);                 // rows 8..11
    const int  gy1  = y0 + trow + 6;
    const bool lv1  = act1 && ((unsigned)gy1 < 128u);
    const int  off1 = (lv1 ? gy1 : 0) * 32 + col;

    // ---- s1 ragged rows {0,9} on tid<64 (primary row trow+1 is mask-free) --
    const bool  sact1 = (tid < 64);
    const int   sr  = (tid < 32) ? 0 : 9;
    const float m1  = ((unsigned)(y0 + sr - 1) < 128u) ? 1.f : 0.f;
    const int   ci1 = (sr + 1) * 32 + (tid & 31);  // input center for row sr
    const int   so1 = sr * 32 + (tid & 31);        // s1-plane store index

    const float lmask = (col == 0)  ? 0.f : 1.f;   // x=0 edge
    const float rmask = (col == 31) ? 0.f : 1.f;   // x=127 edge

    const int go4 = (y0 + trow) * 32 + col;        // owned global f4 offset

    const float4 f4z = make_float4(0.f, 0.f, 0.f, 0.f);
    float4 pf0 = f4z, pf1 = f4z;
    float4 s_m = f4z, s_c = f4z, s_p = f4z;        // s1 chain (rows trow+1)

    auto prefetch = [&](int L) {
        pf0 = f4z; pf1 = f4z;
        if ((unsigned)L < 128u) {
            const float4* zp = sp + ((size_t)L << 12);
            if (lv0) pf0 = zp[off0];
            if (lv1) pf1 = zp[off1];
        }
    };
    auto commit = [&](int L) {
        float4* sl = lin + SLOT4(L) * IN_P4;
        sl[tid] = pf0;
        if (act1) sl[256 + tid] = pf1;
    };
    // s1 at input center ci (reads c,u,d from pzc; m,p from pzm/pzp)
    auto s1one = [&](const float4* pzm, const float4* pzc, const float4* pzp,
                     int ci, float ym) -> float4 {
        float4 qC = pzc[ci];
        float4 qU = pzc[ci - 32];
        float4 qD = pzc[ci + 32];
        float4 qm = pzm[ci];
        float4 qp = pzp[ci];
        float lf = __shfl_up(qC.w, 1, 64)   * lmask;
        float rt = __shfl_down(qC.x, 1, 64) * rmask;
        float4 v;
        v.x = fmaxf((qC.x + lf   + qC.y + qU.x + qD.x + qm.x + qp.x) * wk + bs, 0.f) * ym;
        v.y = fmaxf((qC.y + qC.x + qC.z + qU.y + qD.y + qm.y + qp.y) * wk + bs, 0.f) * ym;
        v.z = fmaxf((qC.z + qC.y + qC.w + qU.z + qD.z + qm.z + qp.z) * wk + bs, 0.f) * ym;
        v.w = fmaxf((qC.w + qC.z + rt   + qU.w + qD.w + qm.w + qp.w) * wk + bs, 0.f) * ym;
        return v;
    };
    // computes s1 plane z (primary row trow+1 -> chain + LDS; ragged -> LDS)
    auto s1_phase = [&](int z) {
        float4* o = ls1 + SLOT2(z) * S1_P4;
        float4 vnew;
        if ((unsigned)z < 128u) {
            const float4* pzm = lin + SLOT4(z - 1) * IN_P4;
            const float4* pzc = lin + SLOT4(z)     * IN_P4;
            const float4* pzp = lin + SLOT4(z + 1) * IN_P4;
            vnew = s1one(pzm, pzc, pzp, tid + 64, 1.f);   // input row trow+2
            o[tid + 32] = vnew;                           // s1 row trow+1
            if (sact1) o[so1] = s1one(pzm, pzc, pzp, ci1, m1);
        } else {
            vnew = f4z;
            o[tid + 32] = f4z;
            if (sact1) o[so1] = f4z;
        }
        s_m = s_c; s_c = s_p; s_p = vnew;
    };

    double part = 0.0;

    // ---- prologue ----
    prefetch(zb - 2); commit(zb - 2);
    prefetch(zb - 1); commit(zb - 1);
    prefetch(zb);     commit(zb);
    prefetch(zb + 1);
    __syncthreads();
    s1_phase(zb - 1);                       // s_p = s1(zb-1)

    // ---- main loop: ONE barrier per plane ----
    for (int L = zb + 1; L <= zb + 17; ++L) {
        commit(L);                          // writes lin slot L&3
        if (L <= zb + 16) prefetch(L + 1);
        __syncthreads();
        s1_phase(L - 1);                    // reads lin L-2..L; writes ls1 (L-1)&1
        const int zo = L - 2;
        if (zo >= zb) {
            const float4* su = ls1 + SLOT2(zo) * S1_P4;   // written last iter
            float4 u4 = su[tid];            // s1 row trow
            float4 d4 = su[tid + 64];       // s1 row trow+2
            float lf = __shfl_up(s_c.w, 1, 64)   * lmask;
            float rt = __shfl_down(s_c.x, 1, 64) * rmask;
            float4 v;
            v.x = fmaxf((s_c.x + lf    + s_c.y + u4.x + d4.x + s_m.x + s_p.x) * wk + bs, 0.f);
            v.y = fmaxf((s_c.y + s_c.x + s_c.z + u4.y + d4.y + s_m.y + s_p.y) * wk + bs, 0.f);
            v.z = fmaxf((s_c.z + s_c.y + s_c.w + u4.z + d4.z + s_m.z + s_p.z) * wk + bs, 0.f);
            v.w = fmaxf((s_c.w + s_c.z + rt    + u4.w + d4.w + s_m.w + s_p.w) * wk + bs, 0.f);
            if (store) dp[((size_t)zo << 12) + go4] = v;
            float pl = c1 * (s_c.x + s_c.y + s_c.z + s_c.w)
                     + c2 * (v.x   + v.y   + v.z   + v.w);
            part += (double)pl;
        }
    }

    // ---- block reduction; slot bid is private to this block ----
    #pragma unroll
    for (int off = 32; off > 0; off >>= 1)
        part += __shfl_down(part, off, 64);
    if ((tid & 63) == 0) wsum[tid >> 6] = part;
    __syncthreads();
    if (tid == 0) {
        double tot = (wsum[0] + wsum[1] + wsum[2] + wsum[3]) * (double)weight[bc];
        atomicAdd(&accs[bid], tot);         // contention-free (private slot)
    }
}

// Reduce the NACC per-block accumulators -> scalar mean.
__global__ __launch_bounds__(1024) void finalize_kernel(
    const double* __restrict__ accs, float* __restrict__ out)
{
    __shared__ double wsum[16];
    double v = accs[threadIdx.x];
    #pragma unroll
    for (int off = 32; off > 0; off >>= 1)
        v += __shfl_down(v, off, 64);
    int lane = threadIdx.x & 63;
    int wid  = threadIdx.x >> 6;
    if (lane == 0) wsum[wid] = v;
    __syncthreads();
    if (threadIdx.x == 0) {
        double tot = 0.0;
        #pragma unroll
        for (int i = 0; i < 16; ++i) tot += wsum[i];
        out[0] = (float)(tot / (double)NTOT);
    }
}

extern "C" void kernel_launch(void* const* d_in, const int* in_sizes, int n_in,
                              void* d_out, int out_size, void* d_ws, size_t ws_size,
                              hipStream_t stream) {
    const float* in     = (const float*)d_in[0];
    const int*   tgt    = (const int*)d_in[1];
    const float* weight = (const float*)d_in[2];
    const float* kern   = (const float*)d_in[3];
    const float* bias   = (const float*)d_in[4];
    float* out = (float*)d_out;

    char* ws = (char*)d_ws;
    float* buf0 = (float*)ws;
    float* buf1 = (float*)(ws + (size_t)NTOT * sizeof(float));
    double* accs = (double*)(ws + (size_t)NTOT * 2 * sizeof(float));

    // 1) softmax + one-hot + square (also zeroes accs)
    softmax_sq_kernel<<<(NSITE / 16) / 256, 256, 0, stream>>>(in, tgt, buf0, accs);

    // 2) 5 fused double-erosion passes; last pass skips the store
    float* cur = buf0;
    float* nxt = buf1;
    for (int p = 0; p < 5; ++p) {
        float c1 = (float)((2 * p + 1) * (2 * p + 1));
        float c2 = (float)((2 * p + 2) * (2 * p + 2));
        int   store = (p < 4) ? 1 : 0;
        erode2_kernel<<<1024, 256, 0, stream>>>(
            (const float4*)cur, (float4*)nxt, kern, bias, weight, c1, c2, store, accs);
        float* t = cur; cur = nxt; nxt = t;
    }

    // 3) reduce + mean
    finalize_kernel<<<1, 1024, 0, stream>>>(accs, out);
}